// Round 3
// baseline (2349.201 us; speedup 1.0000x reference)
//
#include <hip/hip_runtime.h>
#include <cstdint>

typedef __fp16 half2v __attribute__((ext_vector_type(2)));

#define S_ROW 3080   // dwords per LDS pair-row: blocks of 8 data + 4 pad dwords
#define W 2048
#define H 512

__device__ __forceinline__ half2v as_h2(uint32_t u) {
    union { uint32_t u; half2v h; } x; x.u = u; return x.h;
}
__device__ __forceinline__ uint32_t as_u32(half2v h) {
    union { uint32_t u; half2v h; } x; x.h = h; return x.u;
}

// ---------------- pack recurrent weights into half2 pairs (once, tiny) ----------------
// layout in wpk (uint32 half2 words):
//   [0..107]   group0 (out-pairs 0,2,4): ((op*2+s)*6+cp)*3+k
//   [108..179] group1 (out-pairs 1,3):   ((op*2+s)*6+cp)*3+k
//   [180..184] wop[cp] = (wo[2cp], wo[2cp+1])
__global__ void pack_weights_kernel(const float* __restrict__ wl,
                                    const float* __restrict__ wo,
                                    uint32_t* __restrict__ wpk) {
    int i = threadIdx.x;                 // 64 threads, strided
    for (; i < 185; i += 64) {
        half2v v;
        if (i < 180) {
            int g  = (i < 108) ? 0 : 1;
            int r  = (i < 108) ? i : i - 108;
            int k  = r % 3;
            int cp = (r / 3) % 6;
            int s  = (r / 18) % 2;
            int op = r / 36;
            int c  = 2 * (2 * op + g) + s;
            v.x = (__fp16)wl[(c * 12 + 2 * cp    ) * 3 + k];   // RTN
            v.y = (__fp16)wl[(c * 12 + 2 * cp + 1) * 3 + k];
        } else {
            int cp = i - 180;
            v.x = (__fp16)wo[2 * cp];
            v.y = (__fp16)wo[2 * cp + 1];
        }
        wpk[i] = as_u32(v);
    }
}

// ---------------- recurrence body (NOP = number of out channel-pairs for this wave group) ----------------
template<int NOP>
__device__ __forceinline__ void run_batch(
    int tid, int g,
    const float* __restrict__ x, float* __restrict__ out,
    const uint32_t* __restrict__ wpk,
    const float* __restrict__ bl, const float* __restrict__ bo,
    uint32_t* lds, int b)
{
    const int p = tid & 255;                 // position block within group

    // uniform weight accessors (scalar loads, hoisted/rematerialized on the scalar pipe)
    const uint32_t* wq = wpk + (g == 0 ? 0 : 108);
    #define W_AT(op, s, cp, k)  as_h2(wq[(((op)*2 + (s))*6 + (cp))*3 + (k)])
    #define WOP(cp)             as_h2(wpk[180 + (cp)])

    float bias[NOP][2];
    #pragma unroll
    for (int op = 0; op < NOP; ++op) {
        int P = 2*op + g;
        bias[op][0] = bl[2*P];
        bias[op][1] = bl[2*P + 1];
    }
    const float bov = bo[0];

    float*       outb = out + (size_t)b * H * W;
    const float* x1b  = x + (((size_t)b*3 + 1)*H)*W;
    const float* x2b  = x + (((size_t)b*3 + 2)*H)*W;

    // ---- phase C for t = 0 (row0 already in LDS) ----
    {
        const int idxc = 4*tid + 4*(tid >> 1);
        float o0=bov,o1=bov,o2=bov,o3=bov;
        #pragma unroll
        for (int cp = 0; cp < 5; ++cp) {
            uint4 q = *(const uint4*)&lds[cp*S_ROW + idxc];
            half2v wv = WOP(cp);
            o0 = __builtin_amdgcn_fdot2(wv, as_h2(q.x), o0, false);
            o1 = __builtin_amdgcn_fdot2(wv, as_h2(q.y), o1, false);
            o2 = __builtin_amdgcn_fdot2(wv, as_h2(q.z), o2, false);
            o3 = __builtin_amdgcn_fdot2(wv, as_h2(q.w), o3, false);
        }
        *(float4*)(outb + 4*tid) = make_float4(o0,o1,o2,o3);
    }

    #pragma unroll 1
    for (int t = 1; t < H; ++t) {
        // ---------- phase A: compute new row into registers ----------
        // x pairs for w = 8p..8p+9, packed on the fly
        const float* r1 = x1b + (size_t)t*W + 8*p;
        const float* r2 = x2b + (size_t)t*W + 8*p;
        float4 a0 = *(const float4*)r1;
        float4 a1 = *(const float4*)(r1 + 4);
        float4 c0 = *(const float4*)r2;
        float4 c1 = *(const float4*)(r2 + 4);
        float e1a = 0.f, e1b = 0.f, e2a = 0.f, e2b = 0.f;
        if (p < 255) {
            float2 t1 = *(const float2*)(r1 + 8);
            float2 t2 = *(const float2*)(r2 + 8);
            e1a = t1.x; e1b = t1.y; e2a = t2.x; e2b = t2.y;
        }
        uint32_t xd[10];
        xd[0] = as_u32(__builtin_amdgcn_cvt_pkrtz(a0.x, c0.x));
        xd[1] = as_u32(__builtin_amdgcn_cvt_pkrtz(a0.y, c0.y));
        xd[2] = as_u32(__builtin_amdgcn_cvt_pkrtz(a0.z, c0.z));
        xd[3] = as_u32(__builtin_amdgcn_cvt_pkrtz(a0.w, c0.w));
        xd[4] = as_u32(__builtin_amdgcn_cvt_pkrtz(a1.x, c1.x));
        xd[5] = as_u32(__builtin_amdgcn_cvt_pkrtz(a1.y, c1.y));
        xd[6] = as_u32(__builtin_amdgcn_cvt_pkrtz(a1.z, c1.z));
        xd[7] = as_u32(__builtin_amdgcn_cvt_pkrtz(a1.w, c1.w));
        xd[8] = as_u32(__builtin_amdgcn_cvt_pkrtz(e1a, e2a));
        xd[9] = as_u32(__builtin_amdgcn_cvt_pkrtz(e1b, e2b));

        float acc[NOP][2][8];
        #pragma unroll
        for (int op = 0; op < NOP; ++op)
            #pragma unroll
            for (int s = 0; s < 2; ++s)
                #pragma unroll
                for (int i = 0; i < 8; ++i)
                    acc[op][s][i] = bias[op][s];

        // xi contribution first (loads already in flight)
        #pragma unroll
        for (int op = 0; op < NOP; ++op)
            #pragma unroll
            for (int s = 0; s < 2; ++s)
                #pragma unroll
                for (int k = 0; k < 3; ++k) {
                    half2v wv = W_AT(op, s, 5, k);
                    #pragma unroll
                    for (int i = 0; i < 8; ++i)
                        acc[op][s][i] = __builtin_amdgcn_fdot2(wv, as_h2(xd[i+k]), acc[op][s][i], false);
                }

        // prev-row contribution
        #pragma unroll
        for (int cp = 0; cp < 5; ++cp) {
            const uint32_t* row = &lds[cp*S_ROW + 12*p];
            uint4 fa = *(const uint4*)row;              // w 8p..8p+3
            uint4 fb = *(const uint4*)(row + 4);        // w 8p+4..8p+7
            uint2 fc = *(const uint2*)(row + 12);       // w 8p+8..8p+9 (next block)
            uint32_t fd[10] = {fa.x,fa.y,fa.z,fa.w, fb.x,fb.y,fb.z,fb.w, fc.x,fc.y};
            #pragma unroll
            for (int op = 0; op < NOP; ++op)
                #pragma unroll
                for (int s = 0; s < 2; ++s)
                    #pragma unroll
                    for (int k = 0; k < 3; ++k) {
                        half2v wv = W_AT(op, s, cp, k);
                        #pragma unroll
                        for (int i = 0; i < 8; ++i)
                            acc[op][s][i] = __builtin_amdgcn_fdot2(wv, as_h2(fd[i+k]), acc[op][s][i], false);
                    }
        }

        __syncthreads();   // all reads of prev row done

        // ---------- phase B: relu, pack, write new row ----------
        #pragma unroll
        for (int op = 0; op < NOP; ++op) {
            int P = 2*op + g;
            uint32_t* row = &lds[P*S_ROW];
            uint32_t v[8];
            #pragma unroll
            for (int i = 0; i < 8; ++i) {
                float lo = fmaxf(acc[op][0][i], 0.f);
                float hi = fmaxf(acc[op][1][i], 0.f);
                v[i] = as_u32(__builtin_amdgcn_cvt_pkrtz(lo, hi));
            }
            // w = 8p+1 .. 8p+8  ->  idx 12p+1..12p+7, 12p+12
            if (p < 255) {
                row[12*p + 1] = v[0];
                uint2 v12; v12.x = v[1]; v12.y = v[2];
                *(uint2*)(row + 12*p + 2) = v12;
                uint4 v36; v36.x=v[3]; v36.y=v[4]; v36.z=v[5]; v36.w=v[6];
                *(uint4*)(row + 12*p + 4) = v36;
                row[12*p + 12] = v[7];
            } else {                                     // only w 2041..2046 valid
                row[12*p + 1] = v[0];
                row[12*p + 2] = v[1];
                row[12*p + 3] = v[2];
                row[12*p + 4] = v[3];
                row[12*p + 5] = v[4];
                row[12*p + 6] = v[5];
            }
        }

        __syncthreads();   // new row visible

        // ---------- phase C: fused 1x1 conv -> out row t ----------
        {
            const int idxc = 4*tid + 4*(tid >> 1);
            float o0=bov,o1=bov,o2=bov,o3=bov;
            #pragma unroll
            for (int cp = 0; cp < 5; ++cp) {
                uint4 q = *(const uint4*)&lds[cp*S_ROW + idxc];
                half2v wv = WOP(cp);
                o0 = __builtin_amdgcn_fdot2(wv, as_h2(q.x), o0, false);
                o1 = __builtin_amdgcn_fdot2(wv, as_h2(q.y), o1, false);
                o2 = __builtin_amdgcn_fdot2(wv, as_h2(q.z), o2, false);
                o3 = __builtin_amdgcn_fdot2(wv, as_h2(q.w), o3, false);
            }
            *(float4*)(outb + (size_t)t*W + 4*tid) = make_float4(o0,o1,o2,o3);
        }
    }
    #undef W_AT
    #undef WOP
}

// ---------------- one workgroup per batch ----------------
__global__ __launch_bounds__(512, 2) void recurrent_kernel(
    const float* __restrict__ x,
    const float* __restrict__ w1, const float* __restrict__ b1,
    const float* __restrict__ w2, const float* __restrict__ b2,
    const float* __restrict__ bl, const float* __restrict__ bo,
    const uint32_t* __restrict__ wpk, float* __restrict__ out)
{
    __shared__ uint32_t lds[5 * S_ROW];    // 61.6 KB, half2 channel pairs, block-swizzled
    const int tid = threadIdx.x;
    const int b   = blockIdx.x;

    for (int i = tid; i < 5*S_ROW; i += 512) lds[i] = 0;   // zeros: borders + guard region
    __syncthreads();

    // ---- init: row0 = relu(conv2('same', relu(conv1('valid', first_in)))) padded ----
    {
        const float* f0 = x + (((size_t)b*3 + 0)*H + (H-1))*W;  // x[b,0,-1,:]
        const float* f1 = x + (((size_t)b*3 + 1)*H + 0)*W;      // x[b,1,0,:]
        const float* f2 = x + (((size_t)b*3 + 2)*H + 0)*W;      // x[b,2,0,:]
        float fi[3][8];
        const int v0 = 4*tid - 1;
        #pragma unroll
        for (int l = 0; l < 8; ++l) {
            int v = v0 + l;
            bool ok = (v >= 0) && (v < W);
            fi[0][l] = ok ? f0[v] : 0.f;
            fi[1][l] = ok ? f1[v] : 0.f;
            fi[2][l] = ok ? f2[v] : 0.f;
        }
        float h1v[5][6];
        #pragma unroll
        for (int c = 0; c < 5; ++c)
            #pragma unroll
            for (int i6 = 0; i6 < 6; ++i6) {
                int u = v0 + i6;               // h1 position (valid 0..2045, else 'same' pad 0)
                float a = b1[c];
                #pragma unroll
                for (int j = 0; j < 3; ++j)
                    #pragma unroll
                    for (int k = 0; k < 3; ++k)
                        a += w1[(c*3 + j)*3 + k] * fi[j][i6 + k];
                h1v[c][i6] = (u >= 0 && u <= W-3) ? fmaxf(a, 0.f) : 0.f;
            }
        #pragma unroll
        for (int m = 0; m < 4; ++m) {
            int w = 4*tid + 1 + m;             // row0 interior w = 1..2046
            if (w <= W - 2) {
                float h2c[10];
                #pragma unroll
                for (int c2 = 0; c2 < 10; ++c2) {
                    float a = b2[c2];
                    #pragma unroll
                    for (int c = 0; c < 5; ++c)
                        #pragma unroll
                        for (int k = 0; k < 3; ++k)
                            a += w2[(c2*5 + c)*3 + k] * h1v[c][m + k];
                    h2c[c2] = fmaxf(a, 0.f);
                }
                int idx = w + 4*(w >> 3);
                #pragma unroll
                for (int cp = 0; cp < 5; ++cp)
                    lds[cp*S_ROW + idx] = as_u32(__builtin_amdgcn_cvt_pkrtz(h2c[2*cp], h2c[2*cp+1]));
            }
        }
    }
    __syncthreads();

    const int g = tid >> 8;   // waves 0-3 -> group 0 (6 ch), waves 4-7 -> group 1 (4 ch)
    if (g == 0) run_batch<3>(tid, 0, x, out, wpk, bl, bo, lds, b);
    else        run_batch<2>(tid, 1, x, out, wpk, bl, bo, lds, b);
}

extern "C" void kernel_launch(void* const* d_in, const int* in_sizes, int n_in,
                              void* d_out, int out_size, void* d_ws, size_t ws_size,
                              hipStream_t stream)
{
    const float* x  = (const float*)d_in[0];
    const float* w1 = (const float*)d_in[1];
    const float* b1 = (const float*)d_in[2];
    const float* w2 = (const float*)d_in[3];
    const float* b2 = (const float*)d_in[4];
    const float* wl = (const float*)d_in[5];
    const float* bl = (const float*)d_in[6];
    const float* wo = (const float*)d_in[7];
    const float* bo = (const float*)d_in[8];
    float* out    = (float*)d_out;
    uint32_t* wpk = (uint32_t*)d_ws;    // 185 packed half2 weight words

    pack_weights_kernel<<<1, 64, 0, stream>>>(wl, wo, wpk);
    recurrent_kernel<<<8, 512, 0, stream>>>(x, w1, b1, w2, b2, bl, bo, wpk, out);
}

// Round 4
// 1668.392 us; speedup vs baseline: 1.4081x; 1.4081x over previous
//
#include <hip/hip_runtime.h>
#include <cstdint>

#define W 2048
#define H 512
#define ROWD 6                       // dwords per position (12 halves: 10 row ch + 2 x ch)
#define LDSZ (2050*ROWD + 8)         // ghost pos on each side + OOB-read pad

typedef __fp16 h2    __attribute__((ext_vector_type(2)));
typedef __fp16 f16x8 __attribute__((ext_vector_type(8)));
typedef float  f32x16 __attribute__((ext_vector_type(16)));

static __device__ __forceinline__ h2 as_h2(uint32_t u){ union{uint32_t u; h2 h;} x; x.u=u; return x.h; }
static __device__ __forceinline__ uint32_t as_u32(h2 h){ union{uint32_t u; h2 h;} x; x.h=h; return x.u; }

__global__ __launch_bounds__(512, 2) void recurrent_kernel(
    const float* __restrict__ x,
    const float* __restrict__ w1, const float* __restrict__ b1,
    const float* __restrict__ w2, const float* __restrict__ b2,
    const float* __restrict__ wl, const float* __restrict__ bl,
    const float* __restrict__ wo, const float* __restrict__ bo,
    float* __restrict__ out)
{
    __shared__ uint32_t lds[LDSZ];   // 49.2 KB, position-major f16 rows
    const int tid  = threadIdx.x;
    const int b    = blockIdx.x;
    const int lane = tid & 63;
    const int wv   = tid >> 6;       // wave 0..7
    const int m    = lane & 31;      // MFMA: out-channel row / position col
    const int hh   = lane >> 5;      // k-group select

    for (int i = tid; i < LDSZ; i += 512) lds[i] = 0;

    // ---- A fragments: weights resident in VGPRs for all 512 steps ----
    // A[m][k] = wl[outch=m][inch=k][tap], zero-padded m>=10, k>=12.
    f16x8 afrag[3];
    #pragma unroll
    for (int tap = 0; tap < 3; ++tap)
        #pragma unroll
        for (int j = 0; j < 8; ++j) {
            int k = 8*hh + j;
            float v = (m < 10 && k < 12) ? wl[(m*12 + k)*3 + tap] : 0.f;
            afrag[tap][j] = (__fp16)v;
        }
    // 1x1-conv weight pairs matching this half-wave's D channels
    h2 wop0, wop1, wop2;
    if (hh == 0) {
        wop0 = __builtin_amdgcn_cvt_pkrtz(wo[0], wo[1]);
        wop1 = __builtin_amdgcn_cvt_pkrtz(wo[2], wo[3]);
        wop2 = __builtin_amdgcn_cvt_pkrtz(wo[8], wo[9]);
    } else {
        wop0 = __builtin_amdgcn_cvt_pkrtz(wo[4], wo[5]);
        wop1 = __builtin_amdgcn_cvt_pkrtz(wo[6], wo[7]);
        wop2 = __builtin_amdgcn_cvt_pkrtz(0.f, 0.f);
    }
    // bias preloaded into the accumulator (D rows 0..7 are the valid channels)
    f32x16 bias16;
    #pragma unroll
    for (int r = 0; r < 16; ++r) {
        int ch = (r & 3) + 8*(r >> 2) + 4*hh;
        bias16[r] = (r < 8 && ch < 10) ? bl[ch] : 0.f;
    }
    const float bov = bo[0];
    const int bpaddr = (lane ^ 32) << 2;

    const float* x1b = x + (((size_t)b*3 + 1)*H)*W;
    const float* x2b = x + (((size_t)b*3 + 2)*H)*W;
    float* outb = out + (size_t)b*H*W;

    __syncthreads();   // LDS zeros visible before init writes

    // ---- init: row0 = relu(conv2('same', relu(conv1('valid', first_in)))) ----
    {
        const float* f0p = x + (((size_t)b*3 + 0)*H + (H-1))*W;  // x[b,0,-1,:]
        const float* f1p = x1b;                                   // x[b,1,0,:]
        const float* f2p = x2b;                                   // x[b,2,0,:]
        float fi[3][8];
        const int v0 = 4*tid - 1;
        #pragma unroll
        for (int l = 0; l < 8; ++l) {
            int v = v0 + l;
            bool ok = (v >= 0) && (v < W);
            fi[0][l] = ok ? f0p[v] : 0.f;
            fi[1][l] = ok ? f1p[v] : 0.f;
            fi[2][l] = ok ? f2p[v] : 0.f;
        }
        float h1v[5][6];
        #pragma unroll
        for (int c = 0; c < 5; ++c)
            #pragma unroll
            for (int i6 = 0; i6 < 6; ++i6) {
                int u = v0 + i6;
                float a = b1[c];
                #pragma unroll
                for (int j = 0; j < 3; ++j)
                    #pragma unroll
                    for (int k = 0; k < 3; ++k)
                        a += w1[(c*3 + j)*3 + k] * fi[j][i6 + k];
                h1v[c][i6] = (u >= 0 && u <= W-3) ? fmaxf(a, 0.f) : 0.f;
            }
        #pragma unroll
        for (int mm = 0; mm < 4; ++mm) {
            int w = 4*tid + 1 + mm;            // interior positions 1..2046
            if (w <= W - 2) {
                float h2c[10];
                #pragma unroll
                for (int c2 = 0; c2 < 10; ++c2) {
                    float a = b2[c2];
                    #pragma unroll
                    for (int c = 0; c < 5; ++c)
                        #pragma unroll
                        for (int k = 0; k < 3; ++k)
                            a += w2[(c2*5 + c)*3 + k] * h1v[c][mm + k];
                    h2c[c2] = fmaxf(a, 0.f);
                }
                uint32_t* rp = lds + (size_t)(w + 1)*ROWD;
                #pragma unroll
                for (int cp = 0; cp < 5; ++cp)
                    rp[cp] = as_u32(__builtin_amdgcn_cvt_pkrtz(h2c[2*cp], h2c[2*cp+1]));
            }
        }
        // x channels for step 1
        #pragma unroll
        for (int i = 0; i < 4; ++i) {
            int p = tid + 512*i;
            lds[(p + 1)*ROWD + 5] = as_u32(__builtin_amdgcn_cvt_pkrtz(x1b[W + p], x2b[W + p]));
        }
    }
    __syncthreads();

    // ---- out[0] from row0 (positions 0/2047 are zero rows -> bov automatically) ----
    {
        h2 wo01 = __builtin_amdgcn_cvt_pkrtz(wo[0], wo[1]);
        h2 wo23 = __builtin_amdgcn_cvt_pkrtz(wo[2], wo[3]);
        h2 wo45 = __builtin_amdgcn_cvt_pkrtz(wo[4], wo[5]);
        h2 wo67 = __builtin_amdgcn_cvt_pkrtz(wo[6], wo[7]);
        h2 wo89 = __builtin_amdgcn_cvt_pkrtz(wo[8], wo[9]);
        #pragma unroll
        for (int i = 0; i < 4; ++i) {
            int p = 4*tid + i;
            const uint32_t* rp = lds + (size_t)(p + 1)*ROWD;
            uint2 a = *(const uint2*)rp;
            uint2 c = *(const uint2*)(rp + 2);
            uint32_t e = rp[4];
            float s = __builtin_amdgcn_fdot2(wo01, as_h2(a.x), bov, false);
            s = __builtin_amdgcn_fdot2(wo23, as_h2(a.y), s, false);
            s = __builtin_amdgcn_fdot2(wo45, as_h2(c.x), s, false);
            s = __builtin_amdgcn_fdot2(wo67, as_h2(c.y), s, false);
            s = __builtin_amdgcn_fdot2(wo89, as_h2(e),   s, false);
            outb[p] = s;
        }
    }

    // ---- recurrence: 3 MFMAs per 32-position tile, 8 tiles per wave ----
    #pragma unroll 1
    for (int t = 1; t < H; ++t) {
        uint32_t xst[4];
        const bool pf = (t + 1 < H);
        if (pf) {
            const float* r1 = x1b + (size_t)(t + 1)*W;
            const float* r2 = x2b + (size_t)(t + 1)*W;
            #pragma unroll
            for (int i = 0; i < 4; ++i) {
                int p = tid + 512*i;
                xst[i] = as_u32(__builtin_amdgcn_cvt_pkrtz(r1[p], r2[p]));
            }
        }
        uint32_t stash[8][3];
        #pragma unroll
        for (int ti = 0; ti < 8; ++ti) {
            const int n = (wv*8 + ti)*32 + m;
            f32x16 acc = bias16;
            #pragma unroll
            for (int tap = 0; tap < 3; ++tap) {
                const uint32_t* pb = lds + (size_t)(n + tap)*ROWD + 4*hh;
                uint2 lo = *(const uint2*)pb;
                uint2 hi = *(const uint2*)(pb + 2);
                union { uint32_t u[4]; f16x8 v; } bu;
                bu.u[0] = lo.x; bu.u[1] = lo.y; bu.u[2] = hi.x; bu.u[3] = hi.y;
                acc = __builtin_amdgcn_mfma_f32_32x32x16_f16(afrag[tap], bu.v, acc, 0, 0, 0);
            }
            float f0 = fmaxf(acc[0], 0.f), f1 = fmaxf(acc[1], 0.f);
            float f2 = fmaxf(acc[2], 0.f), f3 = fmaxf(acc[3], 0.f);
            float f4 = fmaxf(acc[4], 0.f), f5 = fmaxf(acc[5], 0.f);
            uint32_t s0 = as_u32(__builtin_amdgcn_cvt_pkrtz(f0, f1));
            uint32_t s1 = as_u32(__builtin_amdgcn_cvt_pkrtz(f2, f3));
            uint32_t s2 = as_u32(__builtin_amdgcn_cvt_pkrtz(f4, f5));
            stash[ti][0] = s0; stash[ti][1] = s1; stash[ti][2] = s2;
            // fused 1x1 conv: this half's channels, then add the other half via bpermute
            float pc = __builtin_amdgcn_fdot2(wop2, as_h2(s2),
                       __builtin_amdgcn_fdot2(wop1, as_h2(s1),
                       __builtin_amdgcn_fdot2(wop0, as_h2(s0), 0.f, false), false), false);
            int pi = __builtin_amdgcn_ds_bpermute(bpaddr, __builtin_bit_cast(int, pc));
            float full = pc + __builtin_bit_cast(float, pi);
            float val = (n == 0 || n == W-1) ? bov : full + bov;
            if (lane < 32) outb[(size_t)t*W + n] = val;
        }
        __syncthreads();   // all reads of row t-1 done
        #pragma unroll
        for (int ti = 0; ti < 8; ++ti) {
            const int n = (wv*8 + ti)*32 + m;
            if (n != 0 && n != W-1) {
                uint32_t* rp = lds + (size_t)(n + 1)*ROWD;
                rp[2*hh]     = stash[ti][0];   // hh0: ch0-1 -> d0 ; hh1: ch4-5 -> d2
                rp[2*hh + 1] = stash[ti][1];   // hh0: ch2-3 -> d1 ; hh1: ch6-7 -> d3
                if (hh == 0) rp[4] = stash[ti][2];  // ch8-9 -> d4
            }
        }
        if (pf) {
            #pragma unroll
            for (int i = 0; i < 4; ++i) {
                int p = tid + 512*i;
                lds[(p + 1)*ROWD + 5] = xst[i];
            }
        }
        __syncthreads();   // row t visible
    }
}

extern "C" void kernel_launch(void* const* d_in, const int* in_sizes, int n_in,
                              void* d_out, int out_size, void* d_ws, size_t ws_size,
                              hipStream_t stream)
{
    const float* x  = (const float*)d_in[0];
    const float* w1 = (const float*)d_in[1];
    const float* b1 = (const float*)d_in[2];
    const float* w2 = (const float*)d_in[3];
    const float* b2 = (const float*)d_in[4];
    const float* wl = (const float*)d_in[5];
    const float* bl = (const float*)d_in[6];
    const float* wo = (const float*)d_in[7];
    const float* bo = (const float*)d_in[8];
    float* out = (float*)d_out;

    recurrent_kernel<<<8, 512, 0, stream>>>(x, w1, b1, w2, b2, wl, bl, wo, bo, out);
}

// Round 6
// 1380.849 us; speedup vs baseline: 1.7013x; 1.2082x over previous
//
#include <hip/hip_runtime.h>
#include <cstdint>

#define W 2048
#define H 512
#define ROWD 6                       // dwords per position (12 halves: 10 row ch + 2 x ch)
#define LDSZ (2050*ROWD + 8)         // ghost pos on each side + OOB-read pad

typedef __fp16 h2    __attribute__((ext_vector_type(2)));
typedef __fp16 f16x8 __attribute__((ext_vector_type(8)));
typedef float  f32x16 __attribute__((ext_vector_type(16)));

static __device__ __forceinline__ h2 as_h2(uint32_t u){ union{uint32_t u; h2 h;} x; x.u=u; return x.h; }
static __device__ __forceinline__ uint32_t as_u32(h2 h){ union{uint32_t u; h2 h;} x; x.h=h; return x.u; }

__global__ __launch_bounds__(1024, 1) void recurrent_kernel(
    const float* __restrict__ x,
    const float* __restrict__ w1, const float* __restrict__ b1,
    const float* __restrict__ w2, const float* __restrict__ b2,
    const float* __restrict__ wl, const float* __restrict__ bl,
    const float* __restrict__ wo, const float* __restrict__ bo,
    float* __restrict__ out)
{
    __shared__ uint32_t lds[LDSZ];   // 49.2 KB, position-major f16 rows
    const int tid  = threadIdx.x;
    const int b    = blockIdx.x;
    const int lane = tid & 63;
    const int wv   = tid >> 6;       // wave 0..15
    const int m    = lane & 31;      // MFMA: out-channel row / position col
    const int hh   = lane >> 5;      // k-group select

    for (int i = tid; i < LDSZ; i += 1024) lds[i] = 0;

    // ---- A fragments: weights resident in VGPRs for all 512 steps ----
    f16x8 afrag[3];
    #pragma unroll
    for (int tap = 0; tap < 3; ++tap)
        #pragma unroll
        for (int j = 0; j < 8; ++j) {
            int k = 8*hh + j;
            float v = (m < 10 && k < 12) ? wl[(m*12 + k)*3 + tap] : 0.f;
            afrag[tap][j] = (__fp16)v;
        }
    // 1x1-conv weight pairs matching this half-wave's D channels
    h2 wop0, wop1, wop2;
    if (hh == 0) {
        wop0 = __builtin_amdgcn_cvt_pkrtz(wo[0], wo[1]);
        wop1 = __builtin_amdgcn_cvt_pkrtz(wo[2], wo[3]);
        wop2 = __builtin_amdgcn_cvt_pkrtz(wo[8], wo[9]);
    } else {
        wop0 = __builtin_amdgcn_cvt_pkrtz(wo[4], wo[5]);
        wop1 = __builtin_amdgcn_cvt_pkrtz(wo[6], wo[7]);
        wop2 = __builtin_amdgcn_cvt_pkrtz(0.f, 0.f);
    }
    // bias preloaded into the accumulator (D rows 0..7 are the valid channels)
    f32x16 bias16;
    #pragma unroll
    for (int r = 0; r < 16; ++r) {
        int ch = (r & 3) + 8*(r >> 2) + 4*hh;
        bias16[r] = (r < 8 && ch < 10) ? bl[ch] : 0.f;
    }
    const float bov = bo[0];
    const int bpaddr = (lane ^ 32) << 2;

    const float* x1b = x + (((size_t)b*3 + 1)*H)*W;
    const float* x2b = x + (((size_t)b*3 + 2)*H)*W;
    float* outb = out + (size_t)b*H*W;

    __syncthreads();   // LDS zeros visible before init writes

    // ---- init: row0 = relu(conv2('same', relu(conv1('valid', first_in)))) ----
    {
        const float* f0p = x + (((size_t)b*3 + 0)*H + (H-1))*W;  // x[b,0,-1,:]
        const float* f1p = x1b;                                   // x[b,1,0,:]
        const float* f2p = x2b;                                   // x[b,2,0,:]
        float fi[3][6];
        const int v0 = 2*tid - 1;      // first_in base position (w-2 of first output)
        #pragma unroll
        for (int l = 0; l < 6; ++l) {
            int v = v0 + l;
            bool ok = (v >= 0) && (v < W);
            fi[0][l] = ok ? f0p[v] : 0.f;
            fi[1][l] = ok ? f1p[v] : 0.f;
            fi[2][l] = ok ? f2p[v] : 0.f;
        }
        float h1v[5][4];
        #pragma unroll
        for (int c = 0; c < 5; ++c)
            #pragma unroll
            for (int i6 = 0; i6 < 4; ++i6) {
                int u = v0 + i6;               // h1 position, valid 0..2045 else 'same' pad 0
                float a = b1[c];
                #pragma unroll
                for (int j = 0; j < 3; ++j)
                    #pragma unroll
                    for (int k = 0; k < 3; ++k)
                        a += w1[(c*3 + j)*3 + k] * fi[j][i6 + k];
                h1v[c][i6] = (u >= 0 && u <= W-3) ? fmaxf(a, 0.f) : 0.f;
            }
        #pragma unroll
        for (int mm = 0; mm < 2; ++mm) {
            int w = 2*tid + 1 + mm;            // interior positions 1..2046
            if (w <= W - 2) {
                float h2c[10];
                #pragma unroll
                for (int c2 = 0; c2 < 10; ++c2) {
                    float a = b2[c2];
                    #pragma unroll
                    for (int c = 0; c < 5; ++c)
                        #pragma unroll
                        for (int k = 0; k < 3; ++k)
                            a += w2[(c2*5 + c)*3 + k] * h1v[c][mm + k];   // h1[w-2..w]
                    h2c[c2] = fmaxf(a, 0.f);
                }
                uint32_t* rp = lds + (size_t)(w + 1)*ROWD;
                #pragma unroll
                for (int cp = 0; cp < 5; ++cp)
                    rp[cp] = as_u32(__builtin_amdgcn_cvt_pkrtz(h2c[2*cp], h2c[2*cp+1]));
            }
        }
        // x channels for step 1
        #pragma unroll
        for (int i = 0; i < 2; ++i) {
            int p = tid + 1024*i;
            lds[(p + 1)*ROWD + 5] = as_u32(__builtin_amdgcn_cvt_pkrtz(x1b[W + p], x2b[W + p]));
        }
    }
    __syncthreads();

    // ---- out[0] from row0 ----
    {
        h2 wo01 = __builtin_amdgcn_cvt_pkrtz(wo[0], wo[1]);
        h2 wo23 = __builtin_amdgcn_cvt_pkrtz(wo[2], wo[3]);
        h2 wo45 = __builtin_amdgcn_cvt_pkrtz(wo[4], wo[5]);
        h2 wo67 = __builtin_amdgcn_cvt_pkrtz(wo[6], wo[7]);
        h2 wo89 = __builtin_amdgcn_cvt_pkrtz(wo[8], wo[9]);
        #pragma unroll
        for (int i = 0; i < 2; ++i) {
            int p = 2*tid + i;
            const uint32_t* rp = lds + (size_t)(p + 1)*ROWD;
            uint2 a = *(const uint2*)rp;
            uint2 c = *(const uint2*)(rp + 2);
            uint32_t e = rp[4];
            float s = __builtin_amdgcn_fdot2(wo01, as_h2(a.x), bov, false);
            s = __builtin_amdgcn_fdot2(wo23, as_h2(a.y), s, false);
            s = __builtin_amdgcn_fdot2(wo45, as_h2(c.x), s, false);
            s = __builtin_amdgcn_fdot2(wo67, as_h2(c.y), s, false);
            s = __builtin_amdgcn_fdot2(wo89, as_h2(e),   s, false);
            outb[p] = s;
        }
    }

    // ---- recurrence: 3 MFMAs per 32-position tile, 4 tiles per wave ----
    #pragma unroll 1
    for (int t = 1; t < H; ++t) {
        uint32_t xst[2];
        const bool pf = (t + 1 < H);
        if (pf) {
            const float* r1 = x1b + (size_t)(t + 1)*W;
            const float* r2 = x2b + (size_t)(t + 1)*W;
            #pragma unroll
            for (int i = 0; i < 2; ++i) {
                int p = tid + 1024*i;
                xst[i] = as_u32(__builtin_amdgcn_cvt_pkrtz(r1[p], r2[p]));
            }
        }
        uint32_t stash[4][3];
        #pragma unroll
        for (int ti = 0; ti < 4; ++ti) {
            const int n = (wv*4 + ti)*32 + m;
            f32x16 acc = bias16;
            #pragma unroll
            for (int tap = 0; tap < 3; ++tap) {
                const uint32_t* pb = lds + (size_t)(n + tap)*ROWD + 4*hh;
                uint2 lo = *(const uint2*)pb;
                uint2 hi = *(const uint2*)(pb + 2);
                union { uint32_t u[4]; f16x8 v; } bu;
                bu.u[0] = lo.x; bu.u[1] = lo.y; bu.u[2] = hi.x; bu.u[3] = hi.y;
                acc = __builtin_amdgcn_mfma_f32_32x32x16_f16(afrag[tap], bu.v, acc, 0, 0, 0);
            }
            float f0 = fmaxf(acc[0], 0.f), f1 = fmaxf(acc[1], 0.f);
            float f2 = fmaxf(acc[2], 0.f), f3 = fmaxf(acc[3], 0.f);
            float f4 = fmaxf(acc[4], 0.f), f5 = fmaxf(acc[5], 0.f);
            uint32_t s0 = as_u32(__builtin_amdgcn_cvt_pkrtz(f0, f1));
            uint32_t s1 = as_u32(__builtin_amdgcn_cvt_pkrtz(f2, f3));
            uint32_t s2 = as_u32(__builtin_amdgcn_cvt_pkrtz(f4, f5));
            stash[ti][0] = s0; stash[ti][1] = s1; stash[ti][2] = s2;
            // fused 1x1 conv: this half's channels, then add the other half via bpermute
            float pc = __builtin_amdgcn_fdot2(wop2, as_h2(s2),
                       __builtin_amdgcn_fdot2(wop1, as_h2(s1),
                       __builtin_amdgcn_fdot2(wop0, as_h2(s0), 0.f, false), false), false);
            int pi = __builtin_amdgcn_ds_bpermute(bpaddr, __builtin_bit_cast(int, pc));
            float full = pc + __builtin_bit_cast(float, pi);
            float val = (n == 0 || n == W-1) ? bov : full + bov;
            if (lane < 32) outb[(size_t)t*W + n] = val;
        }
        __syncthreads();   // all reads of row t-1 done
        #pragma unroll
        for (int ti = 0; ti < 4; ++ti) {
            const int n = (wv*4 + ti)*32 + m;
            if (n != 0 && n != W-1) {
                uint32_t* rp = lds + (size_t)(n + 1)*ROWD;
                rp[2*hh]     = stash[ti][0];   // hh0: ch0-1 -> d0 ; hh1: ch4-5 -> d2
                rp[2*hh + 1] = stash[ti][1];   // hh0: ch2-3 -> d1 ; hh1: ch6-7 -> d3
                if (hh == 0) rp[4] = stash[ti][2];  // ch8-9 -> d4
            }
        }
        if (pf) {
            #pragma unroll
            for (int i = 0; i < 2; ++i) {
                int p = tid + 1024*i;
                lds[(p + 1)*ROWD + 5] = xst[i];
            }
        }
        __syncthreads();   // row t visible
    }
}

extern "C" void kernel_launch(void* const* d_in, const int* in_sizes, int n_in,
                              void* d_out, int out_size, void* d_ws, size_t ws_size,
                              hipStream_t stream)
{
    const float* x  = (const float*)d_in[0];
    const float* w1 = (const float*)d_in[1];
    const float* b1 = (const float*)d_in[2];
    const float* w2 = (const float*)d_in[3];
    const float* b2 = (const float*)d_in[4];
    const float* wl = (const float*)d_in[5];
    const float* bl = (const float*)d_in[6];
    const float* wo = (const float*)d_in[7];
    const float* bo = (const float*)d_in[8];
    float* out = (float*)d_out;

    recurrent_kernel<<<8, 1024, 0, stream>>>(x, w1, b1, w2, b2, wl, bl, wo, bo, out);
}

// Round 7
// 1072.533 us; speedup vs baseline: 2.1903x; 1.2875x over previous
//
#include <hip/hip_runtime.h>
#include <cstdint>

#define W 2048
#define H 512
#define ROWD 6                       // dwords per position (12 halves: 10 row ch + 2 x ch)
#define BUFSZ (2050*ROWD + 8)        // per-buffer dwords (ghost pos each side + OOB pad)

typedef __fp16 h2    __attribute__((ext_vector_type(2)));
typedef __fp16 f16x8 __attribute__((ext_vector_type(8)));
typedef float  f32x16 __attribute__((ext_vector_type(16)));

static __device__ __forceinline__ h2 as_h2(uint32_t u){ union{uint32_t u; h2 h;} x; x.u=u; return x.h; }
static __device__ __forceinline__ uint32_t as_u32(h2 h){ union{uint32_t u; h2 h;} x; x.h=h; return x.u; }

__global__ __launch_bounds__(1024, 1) void recurrent_kernel(
    const float* __restrict__ x,
    const float* __restrict__ w1, const float* __restrict__ b1,
    const float* __restrict__ w2, const float* __restrict__ b2,
    const float* __restrict__ wl, const float* __restrict__ bl,
    const float* __restrict__ wo, const float* __restrict__ bo,
    float* __restrict__ out)
{
    extern __shared__ uint32_t lds[];   // 2 x BUFSZ dwords, double-buffered rows
    const int tid  = threadIdx.x;
    const int b    = blockIdx.x;
    const int lane = tid & 63;
    const int wv   = tid >> 6;       // wave 0..15
    const int m    = lane & 31;      // MFMA: out-channel row / position col
    const int hh   = lane >> 5;      // k-group select

    for (int i = tid; i < 2*BUFSZ; i += 1024) lds[i] = 0;

    // ---- A fragments: weights resident in VGPRs for all 512 steps ----
    f16x8 afrag[3];
    #pragma unroll
    for (int tap = 0; tap < 3; ++tap)
        #pragma unroll
        for (int j = 0; j < 8; ++j) {
            int k = 8*hh + j;
            float v = (m < 10 && k < 12) ? wl[(m*12 + k)*3 + tap] : 0.f;
            afrag[tap][j] = (__fp16)v;
        }
    // 1x1-conv weight pairs matching this half-wave's D channels
    h2 wop0, wop1, wop2;
    if (hh == 0) {
        wop0 = __builtin_amdgcn_cvt_pkrtz(wo[0], wo[1]);
        wop1 = __builtin_amdgcn_cvt_pkrtz(wo[2], wo[3]);
        wop2 = __builtin_amdgcn_cvt_pkrtz(wo[8], wo[9]);
    } else {
        wop0 = __builtin_amdgcn_cvt_pkrtz(wo[4], wo[5]);
        wop1 = __builtin_amdgcn_cvt_pkrtz(wo[6], wo[7]);
        wop2 = __builtin_amdgcn_cvt_pkrtz(0.f, 0.f);
    }
    // bias preloaded into the accumulator (D rows 0..7 are the valid channels)
    f32x16 bias16;
    #pragma unroll
    for (int r = 0; r < 16; ++r) {
        int ch = (r & 3) + 8*(r >> 2) + 4*hh;
        bias16[r] = (r < 8 && ch < 10) ? bl[ch] : 0.f;
    }
    const float bov = bo[0];
    const int bpaddr = (lane ^ 32) << 2;

    const float* x1b = x + (((size_t)b*3 + 1)*H)*W;
    const float* x2b = x + (((size_t)b*3 + 2)*H)*W;
    float* outb = out + (size_t)b*H*W;

    __syncthreads();   // LDS zeros visible before init writes

    // ---- init: row0 = relu(conv2('same', relu(conv1('valid', first_in)))) -> buf0 ----
    {
        const float* f0p = x + (((size_t)b*3 + 0)*H + (H-1))*W;  // x[b,0,-1,:]
        const float* f1p = x1b;                                   // x[b,1,0,:]
        const float* f2p = x2b;                                   // x[b,2,0,:]
        float fi[3][6];
        const int v0 = 2*tid - 1;      // first_in base position (w-2 of first output)
        #pragma unroll
        for (int l = 0; l < 6; ++l) {
            int v = v0 + l;
            bool ok = (v >= 0) && (v < W);
            fi[0][l] = ok ? f0p[v] : 0.f;
            fi[1][l] = ok ? f1p[v] : 0.f;
            fi[2][l] = ok ? f2p[v] : 0.f;
        }
        float h1v[5][4];
        #pragma unroll
        for (int c = 0; c < 5; ++c)
            #pragma unroll
            for (int i6 = 0; i6 < 4; ++i6) {
                int u = v0 + i6;               // h1 position, valid 0..2045 else 'same' pad 0
                float a = b1[c];
                #pragma unroll
                for (int j = 0; j < 3; ++j)
                    #pragma unroll
                    for (int k = 0; k < 3; ++k)
                        a += w1[(c*3 + j)*3 + k] * fi[j][i6 + k];
                h1v[c][i6] = (u >= 0 && u <= W-3) ? fmaxf(a, 0.f) : 0.f;
            }
        #pragma unroll
        for (int mm = 0; mm < 2; ++mm) {
            int w = 2*tid + 1 + mm;            // interior positions 1..2046
            if (w <= W - 2) {
                float h2c[10];
                #pragma unroll
                for (int c2 = 0; c2 < 10; ++c2) {
                    float a = b2[c2];
                    #pragma unroll
                    for (int c = 0; c < 5; ++c)
                        #pragma unroll
                        for (int k = 0; k < 3; ++k)
                            a += w2[(c2*5 + c)*3 + k] * h1v[c][mm + k];   // h1[w-2..w]
                    h2c[c2] = fmaxf(a, 0.f);
                }
                uint32_t* rp = lds + (size_t)(w + 1)*ROWD;
                #pragma unroll
                for (int cp = 0; cp < 5; ++cp)
                    rp[cp] = as_u32(__builtin_amdgcn_cvt_pkrtz(h2c[2*cp], h2c[2*cp+1]));
            }
        }
        // x channels for step 1 -> buf0
        #pragma unroll
        for (int i = 0; i < 2; ++i) {
            int p = tid + 1024*i;
            lds[(p + 1)*ROWD + 5] = as_u32(__builtin_amdgcn_cvt_pkrtz(x1b[W + p], x2b[W + p]));
        }
    }
    __syncthreads();

    // ---- out[0] from row0 ----
    {
        h2 wo01 = __builtin_amdgcn_cvt_pkrtz(wo[0], wo[1]);
        h2 wo23 = __builtin_amdgcn_cvt_pkrtz(wo[2], wo[3]);
        h2 wo45 = __builtin_amdgcn_cvt_pkrtz(wo[4], wo[5]);
        h2 wo67 = __builtin_amdgcn_cvt_pkrtz(wo[6], wo[7]);
        h2 wo89 = __builtin_amdgcn_cvt_pkrtz(wo[8], wo[9]);
        #pragma unroll
        for (int i = 0; i < 2; ++i) {
            int p = 2*tid + i;
            const uint32_t* rp = lds + (size_t)(p + 1)*ROWD;
            uint2 a = *(const uint2*)rp;
            uint2 c = *(const uint2*)(rp + 2);
            uint32_t e = rp[4];
            float s = __builtin_amdgcn_fdot2(wo01, as_h2(a.x), bov, false);
            s = __builtin_amdgcn_fdot2(wo23, as_h2(a.y), s, false);
            s = __builtin_amdgcn_fdot2(wo45, as_h2(c.x), s, false);
            s = __builtin_amdgcn_fdot2(wo67, as_h2(c.y), s, false);
            s = __builtin_amdgcn_fdot2(wo89, as_h2(e),   s, false);
            outb[p] = s;
        }
    }

    // ---- recurrence: single barrier per step (double-buffered rows) ----
    #pragma unroll 1
    for (int t = 1; t < H; ++t) {
        const uint32_t* rb = lds + ((t - 1) & 1)*BUFSZ;   // row t-1 + x[t]
        uint32_t*       wb = lds + (t & 1)*BUFSZ;         // row t   + x[t+1]

        // prefetch x[t+1] (raw floats; converted in phase B so loads get cover)
        float xf1[2], xf2[2];
        const bool pf = (t + 1 < H);
        if (pf) {
            const float* r1 = x1b + (size_t)(t + 1)*W;
            const float* r2 = x2b + (size_t)(t + 1)*W;
            #pragma unroll
            for (int i = 0; i < 2; ++i) {
                int p = tid + 1024*i;
                xf1[i] = r1[p];
                xf2[i] = r2[p];
            }
        }

        // phase A: issue all B-fragment loads, then MFMA chains
        uint32_t bu[4][3][4];
        #pragma unroll
        for (int ti = 0; ti < 4; ++ti) {
            const int n = (wv*4 + ti)*32 + m;
            #pragma unroll
            for (int tap = 0; tap < 3; ++tap) {
                const uint32_t* pb = rb + (size_t)(n + tap)*ROWD + 4*hh;
                uint2 lo = *(const uint2*)pb;
                uint2 hi = *(const uint2*)(pb + 2);
                bu[ti][tap][0] = lo.x; bu[ti][tap][1] = lo.y;
                bu[ti][tap][2] = hi.x; bu[ti][tap][3] = hi.y;
            }
        }
        uint32_t stash[4][3];
        float pv[4];
        #pragma unroll
        for (int ti = 0; ti < 4; ++ti) {
            f32x16 acc = bias16;
            #pragma unroll
            for (int tap = 0; tap < 3; ++tap) {
                union { uint32_t u[4]; f16x8 v; } c;
                c.u[0] = bu[ti][tap][0]; c.u[1] = bu[ti][tap][1];
                c.u[2] = bu[ti][tap][2]; c.u[3] = bu[ti][tap][3];
                acc = __builtin_amdgcn_mfma_f32_32x32x16_f16(afrag[tap], c.v, acc, 0, 0, 0);
            }
            float f0 = fmaxf(acc[0], 0.f), f1 = fmaxf(acc[1], 0.f);
            float f2 = fmaxf(acc[2], 0.f), f3 = fmaxf(acc[3], 0.f);
            float f4 = fmaxf(acc[4], 0.f), f5 = fmaxf(acc[5], 0.f);
            uint32_t s0 = as_u32(__builtin_amdgcn_cvt_pkrtz(f0, f1));
            uint32_t s1 = as_u32(__builtin_amdgcn_cvt_pkrtz(f2, f3));
            uint32_t s2 = as_u32(__builtin_amdgcn_cvt_pkrtz(f4, f5));
            stash[ti][0] = s0; stash[ti][1] = s1; stash[ti][2] = s2;
            // fused 1x1 conv: this half's channels + other half via bpermute
            float pc = __builtin_amdgcn_fdot2(wop2, as_h2(s2),
                       __builtin_amdgcn_fdot2(wop1, as_h2(s1),
                       __builtin_amdgcn_fdot2(wop0, as_h2(s0), 0.f, false), false), false);
            int pi = __builtin_amdgcn_ds_bpermute(bpaddr, __builtin_bit_cast(int, pc));
            pv[ti] = pc + __builtin_bit_cast(float, pi);
        }

        // phase B: write row t into wb (no conflict with rb)
        #pragma unroll
        for (int ti = 0; ti < 4; ++ti) {
            const int n = (wv*4 + ti)*32 + m;
            if (n != 0 && n != W-1) {
                uint32_t* rp = wb + (size_t)(n + 1)*ROWD;
                rp[2*hh]     = stash[ti][0];   // hh0: ch0-1 ; hh1: ch4-5
                rp[2*hh + 1] = stash[ti][1];   // hh0: ch2-3 ; hh1: ch6-7
                if (hh == 0) rp[4] = stash[ti][2];  // ch8-9
            }
        }
        if (pf) {
            #pragma unroll
            for (int i = 0; i < 2; ++i) {
                int p = tid + 1024*i;
                wb[(p + 1)*ROWD + 5] = as_u32(__builtin_amdgcn_cvt_pkrtz(xf1[i], xf2[i]));
            }
        }

        __syncthreads();   // row t visible; only barrier in the step

        // deferred out-store: drains at the NEXT step's barrier (a full phase A away)
        if (lane < 32) {
            #pragma unroll
            for (int ti = 0; ti < 4; ++ti) {
                const int n = (wv*4 + ti)*32 + m;
                float val = (n == 0 || n == W-1) ? bov : pv[ti] + bov;
                outb[(size_t)t*W + n] = val;
            }
        }
    }
}

extern "C" void kernel_launch(void* const* d_in, const int* in_sizes, int n_in,
                              void* d_out, int out_size, void* d_ws, size_t ws_size,
                              hipStream_t stream)
{
    const float* x  = (const float*)d_in[0];
    const float* w1 = (const float*)d_in[1];
    const float* b1 = (const float*)d_in[2];
    const float* w2 = (const float*)d_in[3];
    const float* b2 = (const float*)d_in[4];
    const float* wl = (const float*)d_in[5];
    const float* bl = (const float*)d_in[6];
    const float* wo = (const float*)d_in[7];
    const float* bo = (const float*)d_in[8];
    float* out = (float*)d_out;

    const int shbytes = 2 * BUFSZ * sizeof(uint32_t);   // ~98.5 KB
    hipFuncSetAttribute((const void*)recurrent_kernel,
                        hipFuncAttributeMaxDynamicSharedMemorySize, shbytes);
    recurrent_kernel<<<8, 1024, shbytes, stream>>>(x, w1, b1, w2, b2, wl, bl, wo, bo, out);
}